// Round 11
// baseline (18709.427 us; speedup 1.0000x reference)
//
#include <hip/hip_runtime.h>
#include <math.h>

typedef __attribute__((ext_vector_type(2))) double f64x2;
typedef __attribute__((ext_vector_type(4))) float f32x4;

// ---------------- Wp -> B^T fp64, layout [n][k], k=(ky*9+kx)*256+ci -------------
__global__ __launch_bounds__(256) void k_w64(const float* __restrict__ Wp,
                                             double* __restrict__ wT) {
  int oc = blockIdx.x;
  for (int k = threadIdx.x; k < 20736; k += 256) {
    int t = k >> 8, ci = k & 255;
    wT[(size_t)oc * 20736 + k] = (double)Wp[(size_t)oc * 20736 + (size_t)ci * 81 + t];
  }
}

// ---------------- Conv1: 1->256 k9 s1, fp64, out NHWC fp64 (quarter batch) ------
__global__ __launch_bounds__(256) void k_conv1_64(const float* __restrict__ x,
                                                  const float* __restrict__ Wc,
                                                  const float* __restrict__ bc,
                                                  double* __restrict__ h) {
  int b = blockIdx.x >> 1;
  int rh = (blockIdx.x & 1) * 10;
  int oc = threadIdx.x;
  __shared__ float xs[784];
  for (int i = threadIdx.x; i < 784; i += 256) xs[i] = x[(size_t)b * 784 + i];
  __syncthreads();
  float w[81];
#pragma unroll
  for (int t = 0; t < 81; t++) w[t] = Wc[(size_t)oc * 81 + t];
  double bias = (double)bc[oc];
  for (int oh = rh; oh < rh + 10; oh++) {
    for (int ow4 = 0; ow4 < 20; ow4 += 4) {
      double a0 = bias, a1 = bias, a2 = bias, a3 = bias;
#pragma unroll
      for (int ky = 0; ky < 9; ky++) {
        const float* xr = &xs[(oh + ky) * 28 + ow4];
#pragma unroll
        for (int kx = 0; kx < 9; kx++) {
          double wv = (double)w[ky * 9 + kx];
          a0 += wv * (double)xr[kx + 0];
          a1 += wv * (double)xr[kx + 1];
          a2 += wv * (double)xr[kx + 2];
          a3 += wv * (double)xr[kx + 3];
        }
      }
      size_t base = ((size_t)(b * 20 + oh) * 20 + ow4) * 256 + oc;
      h[base + 0]   = fmax(a0, 0.0);
      h[base + 256] = fmax(a1, 0.0);
      h[base + 512] = fmax(a2, 0.0);
      h[base + 768] = fmax(a3, 0.0);
    }
  }
}

// ---------------- Conv2 implicit GEMM, pure fp64 VALU (quarter batch) -----------
__global__ __launch_bounds__(256) void k_conv2_64(const double* __restrict__ h,
                                                  const double* __restrict__ wT,
                                                  double* __restrict__ uraw) {
  int bid = blockIdx.x;
  int mt = bid >> 2, nt = bid & 3;
  int m0 = mt * 64, n0 = nt * 64;
  __shared__ double As[64][18];
  __shared__ double Bs[64][18];
  int tid = threadIdx.x;
  int srow = tid >> 2, scol = (tid & 3) * 4;

  int m = m0 + srow;
  int b = m / 36, sp = m % 36;
  int oh2 = sp / 6, ow2 = sp % 6;
  size_t abase = ((size_t)((b * 20 + 2 * oh2) * 20 + 2 * ow2)) * 256 + scol;
  size_t bbase = (size_t)(n0 + srow) * 20736 + scol;

  int ty = tid >> 4, tx = tid & 15;
  double acc[4][4];
#pragma unroll
  for (int i = 0; i < 4; i++)
#pragma unroll
    for (int j = 0; j < 4; j++) acc[i][j] = 0.0;

  for (int ks = 0; ks < 1296; ks++) {
    int k = ks * 16;
    int t = k >> 8, ci = k & 255;
    int koff = ((t / 9) * 20 + (t % 9)) * 256 + ci;
    __syncthreads();
    {
      const double* ga = h + abase + koff;
      f64x2 a0 = *(const f64x2*)ga;
      f64x2 a1 = *(const f64x2*)(ga + 2);
      *(f64x2*)&As[srow][scol]     = a0;
      *(f64x2*)&As[srow][scol + 2] = a1;
      const double* gb = wT + bbase + k;
      f64x2 b0 = *(const f64x2*)gb;
      f64x2 b1 = *(const f64x2*)(gb + 2);
      *(f64x2*)&Bs[srow][scol]     = b0;
      *(f64x2*)&Bs[srow][scol + 2] = b1;
    }
    __syncthreads();
#pragma unroll
    for (int kk = 0; kk < 16; kk++) {
      double av[4], bv[4];
#pragma unroll
      for (int i = 0; i < 4; i++) av[i] = As[ty * 4 + i][kk];
#pragma unroll
      for (int j = 0; j < 4; j++) bv[j] = Bs[tx * 4 + j][kk];
#pragma unroll
      for (int i = 0; i < 4; i++)
#pragma unroll
        for (int j = 0; j < 4; j++) acc[i][j] = fma(av[i], bv[j], acc[i][j]);
    }
  }

#pragma unroll
  for (int i = 0; i < 4; i++)
#pragma unroll
    for (int j = 0; j < 4; j++)
      uraw[(size_t)(m0 + ty * 4 + i) * 256 + (n0 + tx * 4 + j)] = acc[i][j];
}

// ---------------- squash of primary capsules (fp64) -----------------------------
__global__ __launch_bounds__(256) void k_squash64(const double* __restrict__ uraw,
                                                  const float* __restrict__ bp,
                                                  double* __restrict__ u) {
  int idx = blockIdx.x * 256 + threadIdx.x;  // (b,c): 512*1152
  int b = idx / 1152, c = idx % 1152;
  int f0 = c * 8;
  double v[8];
  double ns = 0.0;
#pragma unroll
  for (int i = 0; i < 8; i++) {
    int f = f0 + i;
    int ch = f / 36, sp = f % 36;  // flat (B,256,6,6): caps of 8 along (ch,h,w) flat
    double val = uraw[((size_t)b * 36 + sp) * 256 + ch] + (double)bp[ch];
    v[i] = val;
    ns += val * val;
  }
  double sc = (ns / (1.0 + ns)) / (0.001 + sqrt(ns));
#pragma unroll
  for (int i = 0; i < 8; i++) u[(size_t)idx * 8 + i] = v[i] * sc;
}

// ---------------- u_hat fp64, eighth batch (bl in [0,64)) -----------------------
__global__ __launch_bounds__(320) void k_uhat64(const double* __restrict__ u,
                                                const float* __restrict__ Wd,
                                                double* __restrict__ uhat, int b0) {
  int c = blockIdx.x;
  int t = threadIdx.x;
  int jo = t % 160, half = t / 160;
  double w[8];
#pragma unroll
  for (int i = 0; i < 8; i++) w[i] = (double)Wd[((size_t)c * 160 + jo) * 8 + i];
  for (int it = 0; it < 32; it++) {
    int bl = it * 2 + half;
    const double* up = u + ((size_t)(b0 + bl) * 1152 + c) * 8;
    double s = 0.0;
#pragma unroll
    for (int i = 0; i < 8; i++) s += w[i] * up[i];
    uhat[((size_t)bl * 1152 + c) * 160 + jo] = s;
  }
}

// ---------------- c_ij = softmax(b_ij) fp64 (eighth batch) ----------------------
__global__ __launch_bounds__(256) void k_cij(const double* __restrict__ bij,
                                             double* __restrict__ cij) {
  int bl = blockIdx.x;
  for (int c = threadIdx.x; c < 1152; c += 256) {
    const double* bp_ = bij + ((size_t)bl * 1152 + c) * 10;
    double bv[10], mx = -1e300;
#pragma unroll
    for (int j = 0; j < 10; j++) { bv[j] = bp_[j]; mx = fmax(mx, bv[j]); }
    double s = 0.0;
#pragma unroll
    for (int j = 0; j < 10; j++) { bv[j] = exp(bv[j] - mx); s += bv[j]; }
    double inv = 1.0 / s;
    double* cp = cij + ((size_t)bl * 1152 + c) * 10;
#pragma unroll
    for (int j = 0; j < 10; j++) cp[j] = bv[j] * inv;
  }
}

// ---------------- routing s_j pass fp64 (+ np-fp32-canonical epilogue on IT==2) -
template <int IT>
__global__ __launch_bounds__(320) void k_route_s(const double* __restrict__ uhat,
                                                 const double* __restrict__ cij,
                                                 double* __restrict__ sj,
                                                 float* __restrict__ vout,
                                                 float* __restrict__ idxout, int b0) {
#pragma clang fp contract(off)
  __shared__ double red[320];
  __shared__ float vsh[160];
  __shared__ float len32[10];
  int bl = blockIdx.x;
  int tid = threadIdx.x;
  int jo = tid % 160, half = tid / 160;
  int j = jo >> 4;
  double acc = 0.0;
  const double* up = uhat + (size_t)bl * 1152 * 160 + jo;
  const double* cp = cij + (size_t)bl * 1152 * 10 + j;
  int c0 = half * 576;
  for (int c = c0; c < c0 + 576; c++) {
    double uv = up[(size_t)c * 160];
    if (IT > 0) acc += cp[(size_t)c * 10] * uv;
    else acc += uv;
  }
  red[tid] = acc;
  __syncthreads();
  if (tid < 160) {
    double s = red[tid] + red[tid + 160];
    if (IT == 0) s *= 0.1;  // softmax of zeros over 10
    sj[(size_t)bl * 160 + tid] = s;
    red[tid] = s;
  }
  if (IT == 2) {
    __syncthreads();
    if (tid < 10) {
      // numpy-fp32 squash chain from fp32-cast s (pairwise-16 trees, mul-then-div)
      float s32[16], a[16];
#pragma unroll
      for (int o = 0; o < 16; o++) { s32[o] = (float)red[tid * 16 + o]; a[o] = s32[o] * s32[o]; }
      float r[8];
#pragma unroll
      for (int k = 0; k < 8; k++) r[k] = a[k] + a[k + 8];
      float ns = ((r[0] + r[1]) + (r[2] + r[3])) + ((r[4] + r[5]) + (r[6] + r[7]));
      float A = ns / (1.0f + ns);
      float D = 0.001f + sqrtf(ns);
#pragma unroll
      for (int o = 0; o < 16; o++) {
        float v = A * (s32[o] / D);
        vsh[tid * 16 + o] = v;
        a[o] = v * v;
      }
#pragma unroll
      for (int k = 0; k < 8; k++) r[k] = a[k] + a[k + 8];
      float nv = ((r[0] + r[1]) + (r[2] + r[3])) + ((r[4] + r[5]) + (r[6] + r[7]));
      len32[tid] = sqrtf(nv);
    }
    __syncthreads();
    if (tid < 160) vout[(size_t)(b0 + bl) * 160 + tid] = vsh[tid];
    if (tid == 0) {
      // fp32 softmax over 10 lengths with correctly-rounded exp, numpy n=10 sum,
      // strict-> first-wins argmax (np semantics)
      float mx = len32[0];
      for (int jj = 1; jj < 10; jj++) mx = fmaxf(mx, len32[jj]);
      float e[10];
      for (int jj = 0; jj < 10; jj++) e[jj] = (float)exp((double)(len32[jj] - mx));
      float ssum = ((e[0] + e[1]) + (e[2] + e[3])) + ((e[4] + e[5]) + (e[6] + e[7]));
      ssum = ssum + e[8];
      ssum = ssum + e[9];
      int best = 0;
      float bst = e[0] / ssum;
      for (int jj = 1; jj < 10; jj++) {
        float p = e[jj] / ssum;
        if (p > bst) { bst = p; best = jj; }
      }
      idxout[b0 + bl] = (float)best;
    }
  }
}

// ---------------- routing agreement update b_ij fp64 ----------------------------
template <bool FIRST>
__global__ __launch_bounds__(256) void k_route_b(const double* __restrict__ uhat,
                                                 const double* __restrict__ sj,
                                                 double* __restrict__ bij) {
  __shared__ double sl[160];
  int bl = blockIdx.x;
  int tid = threadIdx.x;
  if (tid < 160) sl[tid] = sj[(size_t)bl * 160 + tid];
  __syncthreads();
  for (int c = tid; c < 1152; c += 256) {
    const double* up = uhat + ((size_t)bl * 1152 + c) * 160;
    double* bp_ = bij + ((size_t)bl * 1152 + c) * 10;
#pragma unroll
    for (int jj = 0; jj < 10; jj++) {
      double dot = 0.0;
#pragma unroll
      for (int o = 0; o < 16; o++) dot += sl[jj * 16 + o] * up[jj * 16 + o];
      bp_[jj] = (FIRST ? 0.0 : bp_[jj]) + dot;
    }
  }
}

// ---------------- decoder layer 1 (masked input has only 16 nonzeros) -----------
__global__ __launch_bounds__(256) void k_z1(const float* __restrict__ vout,
                                            const int* __restrict__ targets,
                                            const float* __restrict__ W1,
                                            const float* __restrict__ b1,
                                            float* __restrict__ z1) {
  int id = blockIdx.x * 256 + threadIdx.x;
  int b = id >> 9, n = id & 511;
  int t = targets[b];
  float acc = b1[n];
  const float* wr = W1 + (size_t)n * 160 + t * 16;
  const float* vr = vout + (size_t)b * 160 + t * 16;
#pragma unroll
  for (int o = 0; o < 16; o++) acc += wr[o] * vr[o];
  z1[id] = fmaxf(acc, 0.f);
}

// ---------------- generic fp32 GEMM: out[b,n] = act(Z[b,:]·W[n,:] + bias[n]) ----
template <int ACT>
__global__ __launch_bounds__(256) void k_gemm_act(const float* __restrict__ Z,
                                                  const float* __restrict__ W,
                                                  const float* __restrict__ bias,
                                                  float* __restrict__ out, int N, int K) {
  __shared__ float Zt[64][17];
  __shared__ float Wt[64][17];
  int b0 = blockIdx.x * 64;
  int n0 = blockIdx.y * 64;
  int tid = threadIdx.x;
  int ty = tid >> 4, tx = tid & 15;
  int lr = tid >> 2, lc = (tid & 3) * 4;
  float acc[4][4] = {};
  for (int k0 = 0; k0 < K; k0 += 16) {
    __syncthreads();
    f32x4 zv = *(const f32x4*)(Z + (size_t)(b0 + lr) * K + k0 + lc);
    f32x4 wv = {0.f, 0.f, 0.f, 0.f};
    if (n0 + lr < N) wv = *(const f32x4*)(W + (size_t)(n0 + lr) * K + k0 + lc);
    Zt[lr][lc + 0] = zv.x; Zt[lr][lc + 1] = zv.y; Zt[lr][lc + 2] = zv.z; Zt[lr][lc + 3] = zv.w;
    Wt[lr][lc + 0] = wv.x; Wt[lr][lc + 1] = wv.y; Wt[lr][lc + 2] = wv.z; Wt[lr][lc + 3] = wv.w;
    __syncthreads();
#pragma unroll
    for (int kk = 0; kk < 16; kk++) {
      float av[4], bw[4];
#pragma unroll
      for (int i = 0; i < 4; i++) av[i] = Zt[ty * 4 + i][kk];
#pragma unroll
      for (int i = 0; i < 4; i++) bw[i] = Wt[tx * 4 + i][kk];
#pragma unroll
      for (int i = 0; i < 4; i++)
#pragma unroll
        for (int jj = 0; jj < 4; jj++) acc[i][jj] += av[i] * bw[jj];
    }
  }
#pragma unroll
  for (int i = 0; i < 4; i++)
#pragma unroll
    for (int jj = 0; jj < 4; jj++) {
      int bb = b0 + ty * 4 + i;
      int n = n0 + tx * 4 + jj;
      if (n < N) {
        float v = acc[i][jj] + bias[n];
        out[(size_t)bb * N + n] = (ACT == 0) ? fmaxf(v, 0.f) : 1.f / (1.f + __expf(-v));
      }
    }
}

extern "C" void kernel_launch(void* const* d_in, const int* in_sizes, int n_in,
                              void* d_out, int out_size, void* d_ws, size_t ws_size,
                              hipStream_t stream) {
  const float* x       = (const float*)d_in[0];
  const int* targets   = (const int*)d_in[1];
  const float* Wc      = (const float*)d_in[2];
  const float* bc      = (const float*)d_in[3];
  const float* Wp      = (const float*)d_in[4];
  const float* bp      = (const float*)d_in[5];
  const float* Wd      = (const float*)d_in[6];
  const float* W1      = (const float*)d_in[7];
  const float* b1      = (const float*)d_in[8];
  const float* W2      = (const float*)d_in[9];
  const float* b2      = (const float*)d_in[10];
  const float* W3      = (const float*)d_in[11];
  const float* b3      = (const float*)d_in[12];

  char* ws = (char*)d_ws;
  const size_t MB = 1024 * 1024;
  // conv phase (quarters of 128 images):
  double* h64    = (double*)(ws);             // 100 MiB [0,100)
  double* w64T   = (double*)(ws + 100 * MB);  // 40.5    [100,141)
  double* uraw64 = (double*)(ws + 141 * MB);  // 36      [141,177)  full batch
  double* u64    = (double*)(ws + 177 * MB);  // 36      [177,213)  full batch (live thru routing)
  // routing phase, eighths of 64 images (h64/w64T dead; uraw64 dead after squash):
  double* uhat64 = (double*)(ws);             // 90   [0,90)
  double* bij64  = (double*)(ws + 90 * MB);   // 5.63 [90,96)
  double* cij64  = (double*)(ws + 96 * MB);   // 5.63 [96,102)
  double* sj64   = (double*)(ws + 102 * MB);  // 0.08 [102,102.1)
  // decoder (routing buffers dead):
  float* z1      = (float*)(ws + 103 * MB);   // 1 MiB
  float* z2      = (float*)(ws + 104 * MB);   // 2 MiB

  float* vout   = (float*)d_out;                  // [512,10,16]
  float* recon  = (float*)d_out + 81920;          // [512,784]
  float* idxout = (float*)d_out + 81920 + 401408; // [512]

  k_w64<<<256, 256, 0, stream>>>(Wp, w64T);
  for (int q = 0; q < 4; q++) {
    k_conv1_64<<<256, 256, 0, stream>>>(x + (size_t)q * 128 * 784, Wc, bc, h64);
    k_conv2_64<<<288, 256, 0, stream>>>(h64, w64T, uraw64 + (size_t)q * 4608 * 256);
  }
  k_squash64<<<2304, 256, 0, stream>>>(uraw64, bp, u64);
  for (int e = 0; e < 8; e++) {
    int b0 = e * 64;
    k_uhat64<<<1152, 320, 0, stream>>>(u64, Wd, uhat64, b0);
    k_route_s<0><<<64, 320, 0, stream>>>(uhat64, cij64, sj64, vout, idxout, b0);
    k_route_b<true><<<64, 256, 0, stream>>>(uhat64, sj64, bij64);
    k_cij<<<64, 256, 0, stream>>>(bij64, cij64);
    k_route_s<1><<<64, 320, 0, stream>>>(uhat64, cij64, sj64, vout, idxout, b0);
    k_route_b<false><<<64, 256, 0, stream>>>(uhat64, sj64, bij64);
    k_cij<<<64, 256, 0, stream>>>(bij64, cij64);
    k_route_s<2><<<64, 320, 0, stream>>>(uhat64, cij64, sj64, vout, idxout, b0);
  }
  k_z1<<<1024, 256, 0, stream>>>(vout, targets, W1, b1, z1);
  k_gemm_act<0><<<dim3(8, 16), 256, 0, stream>>>(z1, W2, b2, z2, 1024, 512);
  k_gemm_act<1><<<dim3(8, 13), 256, 0, stream>>>(z2, W3, b3, recon, 784, 1024);
}

// Round 12
// 11145.139 us; speedup vs baseline: 1.6787x; 1.6787x over previous
//
#include <hip/hip_runtime.h>
#include <math.h>

typedef __attribute__((ext_vector_type(2))) double f64x2;
typedef __attribute__((ext_vector_type(4))) float f32x4;

// ---------------- Wp -> B^T fp64, layout [n][k], k=(ky*9+kx)*256+ci -------------
__global__ __launch_bounds__(256) void k_w64(const float* __restrict__ Wp,
                                             double* __restrict__ wT) {
  int oc = blockIdx.x;
  for (int k = threadIdx.x; k < 20736; k += 256) {
    int t = k >> 8, ci = k & 255;
    wT[(size_t)oc * 20736 + k] = (double)Wp[(size_t)oc * 20736 + (size_t)ci * 81 + t];
  }
}

// ---------------- Conv1: 1->256 k9 s1, fp64, out NHWC fp64 (quarter batch) ------
__global__ __launch_bounds__(256) void k_conv1_64(const float* __restrict__ x,
                                                  const float* __restrict__ Wc,
                                                  const float* __restrict__ bc,
                                                  double* __restrict__ h) {
  int b = blockIdx.x >> 1;
  int rh = (blockIdx.x & 1) * 10;
  int oc = threadIdx.x;
  __shared__ float xs[784];
  for (int i = threadIdx.x; i < 784; i += 256) xs[i] = x[(size_t)b * 784 + i];
  __syncthreads();
  float w[81];
#pragma unroll
  for (int t = 0; t < 81; t++) w[t] = Wc[(size_t)oc * 81 + t];
  double bias = (double)bc[oc];
  for (int oh = rh; oh < rh + 10; oh++) {
    for (int ow4 = 0; ow4 < 20; ow4 += 4) {
      double a0 = bias, a1 = bias, a2 = bias, a3 = bias;
#pragma unroll
      for (int ky = 0; ky < 9; ky++) {
        const float* xr = &xs[(oh + ky) * 28 + ow4];
#pragma unroll
        for (int kx = 0; kx < 9; kx++) {
          double wv = (double)w[ky * 9 + kx];
          a0 += wv * (double)xr[kx + 0];
          a1 += wv * (double)xr[kx + 1];
          a2 += wv * (double)xr[kx + 2];
          a3 += wv * (double)xr[kx + 3];
        }
      }
      size_t base = ((size_t)(b * 20 + oh) * 20 + ow4) * 256 + oc;
      h[base + 0]   = fmax(a0, 0.0);
      h[base + 256] = fmax(a1, 0.0);
      h[base + 512] = fmax(a2, 0.0);
      h[base + 768] = fmax(a3, 0.0);
    }
  }
}

// ---------------- Conv2 implicit GEMM, fp64 VALU, conflict-free LDS -------------
// M=4608 (quarter), N=256, K=20736. 64x64 tile, BK=16, K ascending (bit-same as
// the passing R11 kernel). Transposed LDS + f64x2 reads + register prefetch.
__global__ __launch_bounds__(256) void k_conv2_64(const double* __restrict__ h,
                                                  const double* __restrict__ wT,
                                                  double* __restrict__ uraw) {
  int bid = blockIdx.x;
  int mt = bid >> 2, nt = bid & 3;
  int m0 = mt * 64, n0 = nt * 64;
  __shared__ __align__(16) double AsT[16][66];  // [k][m]
  __shared__ __align__(16) double BsT[16][66];  // [k][n]
  int tid = threadIdx.x;
  int sm = tid >> 2, sk = (tid & 3) * 4;   // staging: row sm (m or n), 4 k's

  int m = m0 + sm;
  int b = m / 36, sp = m % 36;
  int oh2 = sp / 6, ow2 = sp % 6;
  size_t abase = ((size_t)((b * 20 + 2 * oh2) * 20 + 2 * ow2)) * 256;
  size_t bbase = (size_t)(n0 + sm) * 20736;

  int ty = tid >> 4, tx = tid & 15;
  double acc[4][4];
#pragma unroll
  for (int i = 0; i < 4; i++)
#pragma unroll
    for (int j = 0; j < 4; j++) acc[i][j] = 0.0;

  auto gk = [](int k) -> int {
    int t = k >> 8, ci = k & 255;
    return ((t / 9) * 20 + (t % 9)) * 256 + ci;
  };

  double pa[4], pb[4];
  {
    const double* ga = h + abase + gk(sk);
    pa[0] = ga[0]; pa[1] = ga[1]; pa[2] = ga[2]; pa[3] = ga[3];
    const double* gb = wT + bbase + sk;
    pb[0] = gb[0]; pb[1] = gb[1]; pb[2] = gb[2]; pb[3] = gb[3];
  }

  for (int ks = 0; ks < 1296; ks++) {
    __syncthreads();
    AsT[sk + 0][sm] = pa[0]; AsT[sk + 1][sm] = pa[1];
    AsT[sk + 2][sm] = pa[2]; AsT[sk + 3][sm] = pa[3];
    BsT[sk + 0][sm] = pb[0]; BsT[sk + 1][sm] = pb[1];
    BsT[sk + 2][sm] = pb[2]; BsT[sk + 3][sm] = pb[3];
    __syncthreads();
    if (ks + 1 < 1296) {
      int k = (ks + 1) * 16 + sk;
      const double* ga = h + abase + gk(k);
      pa[0] = ga[0]; pa[1] = ga[1]; pa[2] = ga[2]; pa[3] = ga[3];
      const double* gb = wT + bbase + k;
      pb[0] = gb[0]; pb[1] = gb[1]; pb[2] = gb[2]; pb[3] = gb[3];
    }
#pragma unroll
    for (int kk = 0; kk < 16; kk++) {
      f64x2 al = *(const f64x2*)&AsT[kk][ty * 2];
      f64x2 ah = *(const f64x2*)&AsT[kk][32 + ty * 2];
      f64x2 blo = *(const f64x2*)&BsT[kk][tx * 2];
      f64x2 bhi = *(const f64x2*)&BsT[kk][32 + tx * 2];
      double av[4] = {al.x, al.y, ah.x, ah.y};
      double bv[4] = {blo.x, blo.y, bhi.x, bhi.y};
#pragma unroll
      for (int i = 0; i < 4; i++)
#pragma unroll
        for (int j = 0; j < 4; j++) acc[i][j] = fma(av[i], bv[j], acc[i][j]);
    }
  }

#pragma unroll
  for (int i = 0; i < 4; i++) {
    int r = m0 + ty * 2 + (i & 1) + (i >> 1) * 32;
#pragma unroll
    for (int j = 0; j < 4; j++) {
      int cc = n0 + tx * 2 + (j & 1) + (j >> 1) * 32;
      uraw[(size_t)r * 256 + cc] = acc[i][j];
    }
  }
}

// ---------------- squash of primary capsules (fp64) -----------------------------
__global__ __launch_bounds__(256) void k_squash64(const double* __restrict__ uraw,
                                                  const float* __restrict__ bp,
                                                  double* __restrict__ u) {
  int idx = blockIdx.x * 256 + threadIdx.x;  // (b,c): 512*1152
  int b = idx / 1152, c = idx % 1152;
  int f0 = c * 8;
  double v[8];
  double ns = 0.0;
#pragma unroll
  for (int i = 0; i < 8; i++) {
    int f = f0 + i;
    int ch = f / 36, sp = f % 36;
    double val = uraw[((size_t)b * 36 + sp) * 256 + ch] + (double)bp[ch];
    v[i] = val;
    ns += val * val;
  }
  double sc = (ns / (1.0 + ns)) / (0.001 + sqrt(ns));
#pragma unroll
  for (int i = 0; i < 8; i++) u[(size_t)idx * 8 + i] = v[i] * sc;
}

// ---------------- u_hat fp64, eighth batch (bl in [0,64)) -----------------------
__global__ __launch_bounds__(320) void k_uhat64(const double* __restrict__ u,
                                                const float* __restrict__ Wd,
                                                double* __restrict__ uhat, int b0) {
  int c = blockIdx.x;
  int t = threadIdx.x;
  int jo = t % 160, half = t / 160;
  double w[8];
#pragma unroll
  for (int i = 0; i < 8; i++) w[i] = (double)Wd[((size_t)c * 160 + jo) * 8 + i];
  for (int it = 0; it < 32; it++) {
    int bl = it * 2 + half;
    const double* up = u + ((size_t)(b0 + bl) * 1152 + c) * 8;
    double s = 0.0;
#pragma unroll
    for (int i = 0; i < 8; i++) s += w[i] * up[i];
    uhat[((size_t)bl * 1152 + c) * 160 + jo] = s;
  }
}

// ---------------- c_ij = softmax(b_ij) fp64, wide grid --------------------------
__global__ __launch_bounds__(192) void k_cij(const double* __restrict__ bij,
                                             double* __restrict__ cij) {
  int bl = blockIdx.x;
  int c = blockIdx.y * 192 + threadIdx.x;  // 6*192 = 1152
  const double* bp_ = bij + ((size_t)bl * 1152 + c) * 10;
  double bv[10], mx = -1e300;
#pragma unroll
  for (int j = 0; j < 10; j++) { bv[j] = bp_[j]; mx = fmax(mx, bv[j]); }
  double s = 0.0;
#pragma unroll
  for (int j = 0; j < 10; j++) { bv[j] = exp(bv[j] - mx); s += bv[j]; }
  double inv = 1.0 / s;
  double* cp = cij + ((size_t)bl * 1152 + c) * 10;
#pragma unroll
  for (int j = 0; j < 10; j++) cp[j] = bv[j] * inv;
}

// ---------------- routing s_j pass fp64, wide coalesced grid (bl x j) -----------
template <int IT>
__global__ __launch_bounds__(256) void k_route_s(const double* __restrict__ uhat,
                                                 const double* __restrict__ cij,
                                                 double* __restrict__ sj) {
  int bl = blockIdx.x, j = blockIdx.y;
  int tid = threadIdx.x;
  int o = tid & 15, cl = tid >> 4;
  double acc = 0.0;
  const double* up = uhat + (size_t)bl * 1152 * 160 + j * 16 + o;
  if (IT == 0) {
    for (int c = cl; c < 1152; c += 16) acc += 0.1 * up[(size_t)c * 160];
  } else {
    const double* cp = cij + (size_t)bl * 1152 * 10 + j;
    for (int c = cl; c < 1152; c += 16) acc += cp[(size_t)c * 10] * up[(size_t)c * 160];
  }
  __shared__ double red[256];
  red[tid] = acc;
  __syncthreads();
#pragma unroll
  for (int s = 128; s >= 16; s >>= 1) {
    if (tid < s) red[tid] += red[tid + s];
    __syncthreads();
  }
  if (tid < 16) sj[(size_t)bl * 160 + j * 16 + tid] = red[tid];
}

// ---------------- agreement update b_ij fp64, wide grid -------------------------
// per-(c,j) dot kept in R11's exact sequential-o order.
template <bool FIRST>
__global__ __launch_bounds__(256) void k_route_b(const double* __restrict__ uhat,
                                                 const double* __restrict__ sj,
                                                 double* __restrict__ bij) {
  __shared__ double sl[160];
  int bl = blockIdx.x;
  int tid = threadIdx.x;
  if (tid < 160) sl[tid] = sj[(size_t)bl * 160 + tid];
  __syncthreads();
  int c = blockIdx.y * 128 + (tid >> 1);
  int j0 = (tid & 1) * 5;
  const double* up = uhat + ((size_t)bl * 1152 + c) * 160;
  double* bp_ = bij + ((size_t)bl * 1152 + c) * 10;
#pragma unroll
  for (int jj = 0; jj < 5; jj++) {
    int j = j0 + jj;
    double dot = 0.0;
#pragma unroll
    for (int oo = 0; oo < 16; oo++) dot += sl[j * 16 + oo] * up[j * 16 + oo];
    bp_[j] = (FIRST ? 0.0 : bp_[j]) + dot;
  }
}

// ---------------- epilogue: np-fp32-canonical (verbatim R11 chain) --------------
__global__ __launch_bounds__(192) void k_epi(const double* __restrict__ sj,
                                             float* __restrict__ vout,
                                             float* __restrict__ idxout, int b0) {
#pragma clang fp contract(off)
  __shared__ float vsh[160];
  __shared__ float len32[10];
  int bl = blockIdx.x;
  int tid = threadIdx.x;
  const double* sp = sj + (size_t)bl * 160;
  if (tid < 10) {
    float s32[16], a[16];
#pragma unroll
    for (int o = 0; o < 16; o++) { s32[o] = (float)sp[tid * 16 + o]; a[o] = s32[o] * s32[o]; }
    float r[8];
#pragma unroll
    for (int k = 0; k < 8; k++) r[k] = a[k] + a[k + 8];
    float ns = ((r[0] + r[1]) + (r[2] + r[3])) + ((r[4] + r[5]) + (r[6] + r[7]));
    float A = ns / (1.0f + ns);
    float D = 0.001f + sqrtf(ns);
#pragma unroll
    for (int o = 0; o < 16; o++) {
      float v = A * (s32[o] / D);
      vsh[tid * 16 + o] = v;
      a[o] = v * v;
    }
#pragma unroll
    for (int k = 0; k < 8; k++) r[k] = a[k] + a[k + 8];
    float nv = ((r[0] + r[1]) + (r[2] + r[3])) + ((r[4] + r[5]) + (r[6] + r[7]));
    len32[tid] = sqrtf(nv);
  }
  __syncthreads();
  if (tid < 160) vout[(size_t)(b0 + bl) * 160 + tid] = vsh[tid];
  if (tid == 0) {
    float mx = len32[0];
    for (int jj = 1; jj < 10; jj++) mx = fmaxf(mx, len32[jj]);
    float e[10];
    for (int jj = 0; jj < 10; jj++) e[jj] = (float)exp((double)(len32[jj] - mx));
    float ssum = ((e[0] + e[1]) + (e[2] + e[3])) + ((e[4] + e[5]) + (e[6] + e[7]));
    ssum = ssum + e[8];
    ssum = ssum + e[9];
    int best = 0;
    float bst = e[0] / ssum;
    for (int jj = 1; jj < 10; jj++) {
      float p = e[jj] / ssum;
      if (p > bst) { bst = p; best = jj; }
    }
    idxout[b0 + bl] = (float)best;
  }
}

// ---------------- decoder layer 1 (masked input has only 16 nonzeros) -----------
__global__ __launch_bounds__(256) void k_z1(const float* __restrict__ vout,
                                            const int* __restrict__ targets,
                                            const float* __restrict__ W1,
                                            const float* __restrict__ b1,
                                            float* __restrict__ z1) {
  int id = blockIdx.x * 256 + threadIdx.x;
  int b = id >> 9, n = id & 511;
  int t = targets[b];
  float acc = b1[n];
  const float* wr = W1 + (size_t)n * 160 + t * 16;
  const float* vr = vout + (size_t)b * 160 + t * 16;
#pragma unroll
  for (int o = 0; o < 16; o++) acc += wr[o] * vr[o];
  z1[id] = fmaxf(acc, 0.f);
}

// ---------------- generic fp32 GEMM: out[b,n] = act(Z[b,:]·W[n,:] + bias[n]) ----
template <int ACT>
__global__ __launch_bounds__(256) void k_gemm_act(const float* __restrict__ Z,
                                                  const float* __restrict__ W,
                                                  const float* __restrict__ bias,
                                                  float* __restrict__ out, int N, int K) {
  __shared__ float Zt[64][17];
  __shared__ float Wt[64][17];
  int b0 = blockIdx.x * 64;
  int n0 = blockIdx.y * 64;
  int tid = threadIdx.x;
  int ty = tid >> 4, tx = tid & 15;
  int lr = tid >> 2, lc = (tid & 3) * 4;
  float acc[4][4] = {};
  for (int k0 = 0; k0 < K; k0 += 16) {
    __syncthreads();
    f32x4 zv = *(const f32x4*)(Z + (size_t)(b0 + lr) * K + k0 + lc);
    f32x4 wv = {0.f, 0.f, 0.f, 0.f};
    if (n0 + lr < N) wv = *(const f32x4*)(W + (size_t)(n0 + lr) * K + k0 + lc);
    Zt[lr][lc + 0] = zv.x; Zt[lr][lc + 1] = zv.y; Zt[lr][lc + 2] = zv.z; Zt[lr][lc + 3] = zv.w;
    Wt[lr][lc + 0] = wv.x; Wt[lr][lc + 1] = wv.y; Wt[lr][lc + 2] = wv.z; Wt[lr][lc + 3] = wv.w;
    __syncthreads();
#pragma unroll
    for (int kk = 0; kk < 16; kk++) {
      float av[4], bw[4];
#pragma unroll
      for (int i = 0; i < 4; i++) av[i] = Zt[ty * 4 + i][kk];
#pragma unroll
      for (int i = 0; i < 4; i++) bw[i] = Wt[tx * 4 + i][kk];
#pragma unroll
      for (int i = 0; i < 4; i++)
#pragma unroll
        for (int jj = 0; jj < 4; jj++) acc[i][jj] += av[i] * bw[jj];
    }
  }
#pragma unroll
  for (int i = 0; i < 4; i++)
#pragma unroll
    for (int jj = 0; jj < 4; jj++) {
      int bb = b0 + ty * 4 + i;
      int n = n0 + tx * 4 + jj;
      if (n < N) {
        float v = acc[i][jj] + bias[n];
        out[(size_t)bb * N + n] = (ACT == 0) ? fmaxf(v, 0.f) : 1.f / (1.f + __expf(-v));
      }
    }
}

extern "C" void kernel_launch(void* const* d_in, const int* in_sizes, int n_in,
                              void* d_out, int out_size, void* d_ws, size_t ws_size,
                              hipStream_t stream) {
  const float* x       = (const float*)d_in[0];
  const int* targets   = (const int*)d_in[1];
  const float* Wc      = (const float*)d_in[2];
  const float* bc      = (const float*)d_in[3];
  const float* Wp      = (const float*)d_in[4];
  const float* bp      = (const float*)d_in[5];
  const float* Wd      = (const float*)d_in[6];
  const float* W1      = (const float*)d_in[7];
  const float* b1      = (const float*)d_in[8];
  const float* W2      = (const float*)d_in[9];
  const float* b2      = (const float*)d_in[10];
  const float* W3      = (const float*)d_in[11];
  const float* b3      = (const float*)d_in[12];

  char* ws = (char*)d_ws;
  const size_t MB = 1024 * 1024;
  // conv phase (quarters of 128 images):
  double* h64    = (double*)(ws);             // 100 MiB [0,100)
  double* w64T   = (double*)(ws + 100 * MB);  // 40.5    [100,141)
  double* uraw64 = (double*)(ws + 141 * MB);  // 36      [141,177)  full batch
  double* u64    = (double*)(ws + 177 * MB);  // 36      [177,213)  full batch (live thru routing)
  // routing phase, eighths of 64 images (h64/w64T dead; uraw64 dead after squash):
  double* uhat64 = (double*)(ws);             // 90   [0,90)
  double* bij64  = (double*)(ws + 90 * MB);   // 5.63 [90,96)
  double* cij64  = (double*)(ws + 96 * MB);   // 5.63 [96,102)
  double* sj64   = (double*)(ws + 102 * MB);  // 0.08 [102,102.1)
  // decoder (routing buffers dead):
  float* z1      = (float*)(ws + 103 * MB);   // 1 MiB
  float* z2      = (float*)(ws + 104 * MB);   // 2 MiB

  float* vout   = (float*)d_out;                  // [512,10,16]
  float* recon  = (float*)d_out + 81920;          // [512,784]
  float* idxout = (float*)d_out + 81920 + 401408; // [512]

  k_w64<<<256, 256, 0, stream>>>(Wp, w64T);
  for (int q = 0; q < 4; q++) {
    k_conv1_64<<<256, 256, 0, stream>>>(x + (size_t)q * 128 * 784, Wc, bc, h64);
    k_conv2_64<<<288, 256, 0, stream>>>(h64, w64T, uraw64 + (size_t)q * 4608 * 256);
  }
  k_squash64<<<2304, 256, 0, stream>>>(uraw64, bp, u64);
  for (int e = 0; e < 8; e++) {
    int b0 = e * 64;
    k_uhat64<<<1152, 320, 0, stream>>>(u64, Wd, uhat64, b0);
    k_route_s<0><<<dim3(64, 10), 256, 0, stream>>>(uhat64, cij64, sj64);
    k_route_b<true><<<dim3(64, 9), 256, 0, stream>>>(uhat64, sj64, bij64);
    k_cij<<<dim3(64, 6), 192, 0, stream>>>(bij64, cij64);
    k_route_s<1><<<dim3(64, 10), 256, 0, stream>>>(uhat64, cij64, sj64);
    k_route_b<false><<<dim3(64, 9), 256, 0, stream>>>(uhat64, sj64, bij64);
    k_cij<<<dim3(64, 6), 192, 0, stream>>>(bij64, cij64);
    k_route_s<2><<<dim3(64, 10), 256, 0, stream>>>(uhat64, cij64, sj64);
    k_epi<<<64, 192, 0, stream>>>(sj64, vout, idxout, b0);
  }
  k_z1<<<1024, 256, 0, stream>>>(vout, targets, W1, b1, z1);
  k_gemm_act<0><<<dim3(8, 16), 256, 0, stream>>>(z1, W2, b2, z2, 1024, 512);
  k_gemm_act<1><<<dim3(8, 13), 256, 0, stream>>>(z2, W3, b3, recon, 784, 1024);
}